// Round 3
// baseline (322.532 us; speedup 1.0000x reference)
//
#include <hip/hip_runtime.h>

typedef unsigned short u16;
typedef unsigned int   u32;
typedef unsigned long long u64;
typedef __attribute__((ext_vector_type(4))) float f32x4;
typedef __attribute__((ext_vector_type(8))) short bf16x8;
typedef __attribute__((ext_vector_type(4))) u16  u16x4;
typedef __attribute__((ext_vector_type(8))) u16  u16x8;
typedef __attribute__((ext_vector_type(4))) u32  u32x4;

#define B_  32
#define TQ  1024
#define TK  1024
#define FG  128
#define DV  256

__device__ __forceinline__ u16 f2bf(float x) {
    union { float f; u32 u; } v; v.f = x;
    u32 r = v.u + 0x7fffu + ((v.u >> 16) & 1u);   // RNE
    return (u16)(r >> 16);
}
__device__ __forceinline__ float bf2f(u16 h) {
    union { u32 u; float f; } v; v.u = ((u32)h) << 16;
    return v.f;
}

// ---------------------------------------------------------------------------
// Split+transpose weights: Wq[512,128] -> WqT hi/lo [128,512]; Wk[256,128] -> [128,256]
__global__ void prep_w(const float* __restrict__ Wq, const float* __restrict__ Wk,
                       u16* __restrict__ wqh, u16* __restrict__ wql,
                       u16* __restrict__ wkh, u16* __restrict__ wkl)
{
    const int t = blockIdx.x * 256 + threadIdx.x;
    if (t < 128 * 512) {
        const int n = t >> 9, k = t & 511;
        const float x = Wq[k * FG + n];
        const u16 h = f2bf(x);
        wqh[t] = h; wql[t] = f2bf(x - bf2f(h));
    } else {
        const int u = t - 128 * 512;
        const int n = u >> 8, k = u & 255;
        const float x = Wk[k * FG + n];
        const u16 h = f2bf(x);
        wkh[u] = h; wkl[u] = f2bf(x - bf2f(h));
    }
}

// ---------------------------------------------------------------------------
// v [32,1024,256] fp32 -> vT [32,256,1024] bf16
__global__ __launch_bounds__(256, 1)
void prep_v(const float* __restrict__ v, u16* __restrict__ vT)
{
    __shared__ u16 tile[64][72];
    const int tk0 = blockIdx.x * 64, d0 = blockIdx.y * 64, b = blockIdx.z;
    const int tid = threadIdx.x;
#pragma unroll
    for (int i = 0; i < 4; ++i) {
        const int f4 = i * 256 + tid;
        const int tkr = f4 >> 4, c4 = f4 & 15;
        f32x4 x = *reinterpret_cast<const f32x4*>(v + (u64)b * (TK * DV) + (u64)(tk0 + tkr) * DV + d0 + c4 * 4);
#pragma unroll
        for (int j = 0; j < 4; ++j) tile[tkr][c4 * 4 + j] = f2bf(x[j]);
    }
    __syncthreads();
#pragma unroll
    for (int i = 0; i < 2; ++i) {
        const int idx = i * 256 + tid;
        const int dr = idx >> 3, c8 = idx & 7;
        u16x8 o;
#pragma unroll
        for (int j = 0; j < 8; ++j) o[j] = tile[c8 * 8 + j][dr];
        *reinterpret_cast<u16x8*>(vT + (u64)b * (DV * TK) + (u64)(d0 + dr) * TK + tk0 + c8 * 8) = o;
    }
}

// ---------------------------------------------------------------------------
// Pack mask into per-lane bitmasks matching scores_kernel's layout.
// grid (32 qt, 32 b), 512 threads. Out: mb[((b*32+qt)*512+tid)*2 + {0,1}]
__global__ __launch_bounds__(512, 8)
void mask_pack(const int* __restrict__ mask, u32* __restrict__ mb)
{
    const int qt = blockIdx.x, b = blockIdx.y;
    const int row0 = qt * 32;
    const int tid = threadIdx.x;
    const int wid = tid >> 6, lane = tid & 63;
    const int l16 = lane & 15, l4 = lane >> 4;
    const int* mrow = mask + ((u64)b * TQ + row0) * TK;
    u32 mb0 = 0, mb1 = 0;
#pragma unroll
    for (int mf = 0; mf < 2; ++mf)
#pragma unroll
        for (int r = 0; r < 4; ++r) {
            const int row = mf * 16 + l4 * 4 + r;
#pragma unroll
            for (int nf = 0; nf < 8; ++nf) {
                const int col = wid * 128 + nf * 16 + l16;
                const int idx = mf * 32 + r * 8 + nf;
                const u32 bit = (mrow[(u64)row * TK + col] != 0) ? 1u : 0u;
                if (idx < 32) mb0 |= bit << idx; else mb1 |= bit << (idx - 32);
            }
        }
    const u64 o = ((u64)(b * 32 + qt) * 512 + tid) * 2;
    mb[o] = mb0; mb[o + 1] = mb1;
}

// ---------------------------------------------------------------------------
// Projection GEMM with split-bf16 (3-term) MFMA.
__global__ __launch_bounds__(256, 1)
void proj_kernel(const float* __restrict__ X, const u16* __restrict__ WTh,
                 const u16* __restrict__ WTl, u16* __restrict__ Oh,
                 u16* __restrict__ Ol, const int K, const float scale)
{
    __shared__ char qs[32768];
    char* qsh = qs;
    char* qsl = qs + 16384;
    const int tid = threadIdx.x;
    const int wid = tid >> 6, lane = tid & 63;
    const int l16 = lane & 15, l4 = lane >> 4;
    const int wm = wid >> 1, wn = wid & 1;
    const int rowbase = blockIdx.x * 64;

    f32x4 acc[2][4] = {};
    const int nchunks = K >> 7;
    for (int kc = 0; kc < nchunks; ++kc) {
        if (kc) __syncthreads();
#pragma unroll
        for (int i = 0; i < 8; ++i) {
            const int f4 = i * 256 + tid;
            const int r = f4 >> 5, c4 = f4 & 31;
            f32x4 x = *reinterpret_cast<const f32x4*>(X + (u64)(rowbase + r) * K + kc * 128 + c4 * 4);
            u16x4 hv, lv;
#pragma unroll
            for (int j = 0; j < 4; ++j) {
                const u16 h = f2bf(x[j]);
                hv[j] = h;
                lv[j] = f2bf(x[j] - bf2f(h));
            }
            const u32 a = r * 256 + ((u32)(c4 * 8) ^ ((r & 7) << 4));
            *reinterpret_cast<u16x4*>(qsh + a) = hv;
            *reinterpret_cast<u16x4*>(qsl + a) = lv;
        }
        __syncthreads();
#pragma unroll
        for (int kk = 0; kk < 4; ++kk) {
            bf16x8 ah[2], al[2];
#pragma unroll
            for (int mf = 0; mf < 2; ++mf) {
                const int r = wm * 32 + mf * 16 + l16;
                const u32 kb = kk * 64 + l4 * 16;
                const u32 a = r * 256 + (kb ^ ((u32)(r & 7) << 4));
                ah[mf] = *reinterpret_cast<const bf16x8*>(qsh + a);
                al[mf] = *reinterpret_cast<const bf16x8*>(qsl + a);
            }
#pragma unroll
            for (int nf = 0; nf < 4; ++nf) {
                const int col = wn * 64 + nf * 16 + l16;
                const u64 off = (u64)col * K + kc * 128 + kk * 32 + l4 * 8;
                bf16x8 bh = *reinterpret_cast<const bf16x8*>(WTh + off);
                bf16x8 bl = *reinterpret_cast<const bf16x8*>(WTl + off);
#pragma unroll
                for (int mf = 0; mf < 2; ++mf) {
                    acc[mf][nf] = __builtin_amdgcn_mfma_f32_16x16x32_bf16(ah[mf], bh, acc[mf][nf], 0, 0, 0);
                    acc[mf][nf] = __builtin_amdgcn_mfma_f32_16x16x32_bf16(ah[mf], bl, acc[mf][nf], 0, 0, 0);
                    acc[mf][nf] = __builtin_amdgcn_mfma_f32_16x16x32_bf16(al[mf], bh, acc[mf][nf], 0, 0, 0);
                }
            }
        }
    }
#pragma unroll
    for (int mf = 0; mf < 2; ++mf)
#pragma unroll
        for (int nf = 0; nf < 4; ++nf)
#pragma unroll
            for (int r = 0; r < 4; ++r) {
                const int row = rowbase + wm * 32 + mf * 16 + l4 * 4 + r;
                const int col = wn * 64 + nf * 16 + l16;
                const float xv = acc[mf][nf][r] * scale;
                const u16 h = f2bf(xv);
                Oh[(u64)row * FG + col] = h;
                Ol[(u64)row * FG + col] = f2bf(xv - bf2f(h));
            }
}

// ---------------------------------------------------------------------------
// Scores + mask + softmax + fp32 attn write. No PV, no big LDS.
// grid (32 qt, 32 b), 512 threads (8 waves); wave w owns cols [w*128, w*128+128).
__global__ __launch_bounds__(512, 4)
void scores_kernel(const u16* __restrict__ qp_hi, const u16* __restrict__ qp_lo,
                   const u16* __restrict__ kp_hi, const u16* __restrict__ kp_lo,
                   const u32* __restrict__ mb, float* __restrict__ attn_out)
{
    __shared__ float red[256];
    __shared__ float rowstat[64];

    const int qt = blockIdx.x, b = blockIdx.y;
    const int row0 = qt * 32;
    const int tid = threadIdx.x;
    const int wid = tid >> 6;
    const int lane = tid & 63;
    const int l16 = lane & 15;
    const int l4  = lane >> 4;

    // packed mask: one 8B coalesced load per lane
    const u64 mo = ((u64)(b * 32 + qt) * 512 + tid) * 2;
    const u32 mb0 = mb[mo], mb1 = mb[mo + 1];

    // ---- scores (3-term split-bf16 MFMA); Q frags direct from global (L2-hot) ----
    f32x4 acc[2][8] = {};
    const u16* qph = qp_hi + (u64)(b * TQ + row0) * FG;
    const u16* qpl = qp_lo + (u64)(b * TQ + row0) * FG;
    const u16* kpbh = kp_hi + (u64)b * TK * FG;
    const u16* kpbl = kp_lo + (u64)b * TK * FG;

#pragma unroll
    for (int kk = 0; kk < 4; ++kk) {
        bf16x8 ah[2], al[2];
#pragma unroll
        for (int mf = 0; mf < 2; ++mf) {
            const u64 o = (u64)(mf * 16 + l16) * FG + kk * 32 + l4 * 8;
            ah[mf] = *reinterpret_cast<const bf16x8*>(qph + o);
            al[mf] = *reinterpret_cast<const bf16x8*>(qpl + o);
        }
#pragma unroll
        for (int nf = 0; nf < 8; ++nf) {
            const int col = wid * 128 + nf * 16 + l16;
            const u64 off = (u64)col * FG + kk * 32 + l4 * 8;
            bf16x8 bh = *reinterpret_cast<const bf16x8*>(kpbh + off);
            bf16x8 bl = *reinterpret_cast<const bf16x8*>(kpbl + off);
#pragma unroll
            for (int mf = 0; mf < 2; ++mf) {
                acc[mf][nf] = __builtin_amdgcn_mfma_f32_16x16x32_bf16(ah[mf], bh, acc[mf][nf], 0, 0, 0);
                acc[mf][nf] = __builtin_amdgcn_mfma_f32_16x16x32_bf16(ah[mf], bl, acc[mf][nf], 0, 0, 0);
                acc[mf][nf] = __builtin_amdgcn_mfma_f32_16x16x32_bf16(al[mf], bh, acc[mf][nf], 0, 0, 0);
            }
        }
    }

    // ---- mask apply (pure ALU) ----
#pragma unroll
    for (int mf = 0; mf < 2; ++mf)
#pragma unroll
        for (int r = 0; r < 4; ++r)
#pragma unroll
            for (int nf = 0; nf < 8; ++nf) {
                const int idx = mf * 32 + r * 8 + nf;
                const u32 bit = (idx < 32) ? (mb0 >> idx) : (mb1 >> (idx - 32));
                if (!(bit & 1)) acc[mf][nf][r] = -1e9f;
            }

    // ---- row max ----
#pragma unroll
    for (int mf = 0; mf < 2; ++mf)
#pragma unroll
        for (int r = 0; r < 4; ++r) {
            float m = acc[mf][0][r];
#pragma unroll
            for (int nf = 1; nf < 8; ++nf) m = fmaxf(m, acc[mf][nf][r]);
#pragma unroll
            for (int sh = 1; sh < 16; sh <<= 1) m = fmaxf(m, __shfl_xor(m, sh));
            if (l16 == 0) red[wid * 32 + mf * 16 + l4 * 4 + r] = m;
        }
    __syncthreads();
    if (tid < 32) {
        float m = red[tid];
#pragma unroll
        for (int w = 1; w < 8; ++w) m = fmaxf(m, red[w * 32 + tid]);
        rowstat[tid] = m;
    }
    __syncthreads();

    // ---- exp + row sum ----
#pragma unroll
    for (int mf = 0; mf < 2; ++mf)
#pragma unroll
        for (int r = 0; r < 4; ++r) {
            const int row = mf * 16 + l4 * 4 + r;
            const float m = rowstat[row];
            float s = 0.0f;
#pragma unroll
            for (int nf = 0; nf < 8; ++nf) {
                const float e = __expf(acc[mf][nf][r] - m);
                acc[mf][nf][r] = e;
                s += e;
            }
#pragma unroll
            for (int sh = 1; sh < 16; sh <<= 1) s += __shfl_xor(s, sh);
            if (l16 == 0) red[wid * 32 + row] = s;
        }
    __syncthreads();
    if (tid < 32) {
        float z = red[tid];
#pragma unroll
        for (int w = 1; w < 8; ++w) z += red[w * 32 + tid];
        rowstat[32 + tid] = 1.0f / z;
    }
    __syncthreads();

    // ---- normalize + fp32 attn write ----
    float* aout = attn_out + ((u64)b * TQ + row0) * TK;
#pragma unroll
    for (int mf = 0; mf < 2; ++mf)
#pragma unroll
        for (int r = 0; r < 4; ++r) {
            const int row = mf * 16 + l4 * 4 + r;
            const float rz = rowstat[32 + row];
#pragma unroll
            for (int nf = 0; nf < 8; ++nf) {
                const int col = wid * 128 + nf * 16 + l16;
                aout[(u64)row * TK + col] = acc[mf][nf][r] * rz;
            }
        }
}

// ---------------------------------------------------------------------------
// PV GEMM: ctx[b] = attn[b] (fp32->bf16) @ vT[b]^T. Per block: 64 rows x 128 d.
// grid (32 mn, 32 b): mblk = mn>>1 (16), nblk = mn&1 (2). 256 threads, 2x2 waves.
__global__ __launch_bounds__(256, 4)
void pv_kernel(const float* __restrict__ attn, const u16* __restrict__ vT,
               float* __restrict__ ctx)
{
    __shared__ char as_[16384];   // [64][128] bf16 swizzled
    const int mn = blockIdx.x, b = blockIdx.y;
    const int mblk = mn >> 1, nblk = mn & 1;
    const int row0 = mblk * 64;
    const int tid = threadIdx.x;
    const int wid = tid >> 6, lane = tid & 63;
    const int l16 = lane & 15, l4 = lane >> 4;
    const int wm = wid >> 1, wn = wid & 1;

    const float* Ab = attn + ((u64)b * TQ + row0) * TK;
    const u16*   Bb = vT + (u64)b * DV * TK + (u64)(nblk * 128) * TK;

    f32x4 acc[2][4] = {};
#pragma unroll 1
    for (int kc = 0; kc < 8; ++kc) {
        if (kc) __syncthreads();
        // stage attn [64 rows][128 k] fp32 -> bf16 swizzled LDS
#pragma unroll
        for (int i = 0; i < 8; ++i) {
            const int f4 = i * 256 + tid;
            const int r = f4 >> 5, c4 = f4 & 31;
            f32x4 x = *reinterpret_cast<const f32x4*>(Ab + (u64)r * TK + kc * 128 + c4 * 4);
            u16x4 hv;
#pragma unroll
            for (int j = 0; j < 4; ++j) hv[j] = f2bf(x[j]);
            const u32 a = r * 256 + ((u32)(c4 * 8) ^ ((r & 7) << 4));
            *reinterpret_cast<u16x4*>(as_ + a) = hv;
        }
        __syncthreads();
#pragma unroll
        for (int kk = 0; kk < 4; ++kk) {
            bf16x8 af[2];
#pragma unroll
            for (int mf = 0; mf < 2; ++mf) {
                const int r = wm * 32 + mf * 16 + l16;
                const u32 kb = kk * 64 + l4 * 16;
                af[mf] = *reinterpret_cast<const bf16x8*>(as_ + r * 256 + (kb ^ ((u32)(r & 7) << 4)));
            }
#pragma unroll
            for (int nf = 0; nf < 4; ++nf) {
                const int d = wn * 64 + nf * 16 + l16;
                bf16x8 bv = *reinterpret_cast<const bf16x8*>(Bb + (u64)d * TK + kc * 128 + kk * 32 + l4 * 8);
#pragma unroll
                for (int mf = 0; mf < 2; ++mf)
                    acc[mf][nf] = __builtin_amdgcn_mfma_f32_16x16x32_bf16(af[mf], bv, acc[mf][nf], 0, 0, 0);
            }
        }
    }
    float* cout = ctx + ((u64)b * TQ + row0) * DV + nblk * 128;
#pragma unroll
    for (int mf = 0; mf < 2; ++mf)
#pragma unroll
        for (int nf = 0; nf < 4; ++nf)
#pragma unroll
            for (int r = 0; r < 4; ++r) {
                const int row = wm * 32 + mf * 16 + l4 * 4 + r;
                const int d = wn * 64 + nf * 16 + l16;
                cout[(u64)row * DV + d] = acc[mf][nf][r];
            }
}

// ---------------------------------------------------------------------------
extern "C" void kernel_launch(void* const* d_in, const int* in_sizes, int n_in,
                              void* d_out, int out_size, void* d_ws, size_t ws_size,
                              hipStream_t stream)
{
    const float* q    = (const float*)d_in[0];
    const float* k    = (const float*)d_in[1];
    const float* v    = (const float*)d_in[2];
    const int*   mask = (const int*)d_in[3];
    const float* Wq   = (const float*)d_in[4];
    const float* Wk   = (const float*)d_in[5];

    float* ctx  = (float*)d_out;
    float* attn = ctx + (u64)B_ * TQ * DV;

    u16* p = (u16*)d_ws;
    u16* qp_hi = p; p += (u64)B_ * TQ * FG;
    u16* qp_lo = p; p += (u64)B_ * TQ * FG;
    u16* kp_hi = p; p += (u64)B_ * TK * FG;
    u16* kp_lo = p; p += (u64)B_ * TK * FG;
    u16* vTb   = p; p += (u64)B_ * DV * TK;
    u16* wqh = p; p += 128 * 512;
    u16* wql = p; p += 128 * 512;
    u16* wkh = p; p += 128 * 256;
    u16* wkl = p; p += 128 * 256;
    u32* mb  = (u32*)p;   // 4 MB packed mask

    hipLaunchKernelGGL(mask_pack, dim3(32, 32), dim3(512), 0, stream, mask, mb);
    hipLaunchKernelGGL(prep_w, dim3(384), dim3(256), 0, stream, Wq, Wk, wqh, wql, wkh, wkl);
    hipLaunchKernelGGL(prep_v, dim3(16, 4, 32), dim3(256), 0, stream, v, vTb);
    hipLaunchKernelGGL(proj_kernel, dim3(512), dim3(256), 0, stream, q, wqh, wql, qp_hi, qp_lo, 512, 0.0625f);
    hipLaunchKernelGGL(proj_kernel, dim3(512), dim3(256), 0, stream, k, wkh, wkl, kp_hi, kp_lo, 256, 1.0f);
    hipLaunchKernelGGL(scores_kernel, dim3(32, 32), dim3(512), 0, stream,
                       qp_hi, qp_lo, kp_hi, kp_lo, mb, attn);
    hipLaunchKernelGGL(pv_kernel, dim3(32, 32), dim3(256), 0, stream, attn, vTb, ctx);
}

// Round 4
// 314.861 us; speedup vs baseline: 1.0244x; 1.0244x over previous
//
#include <hip/hip_runtime.h>

typedef unsigned short u16;
typedef unsigned int   u32;
typedef unsigned long long u64;
typedef __attribute__((ext_vector_type(4))) float f32x4;
typedef __attribute__((ext_vector_type(8))) short bf16x8;
typedef __attribute__((ext_vector_type(4))) u16  u16x4;
typedef __attribute__((ext_vector_type(8))) u16  u16x8;
typedef __attribute__((ext_vector_type(4))) u32  u32x4;

#define B_  32
#define TQ  1024
#define TK  1024
#define FG  128
#define DV  256

__device__ __forceinline__ u16 f2bf(float x) {
    union { float f; u32 u; } v; v.f = x;
    u32 r = v.u + 0x7fffu + ((v.u >> 16) & 1u);   // RNE
    return (u16)(r >> 16);
}
__device__ __forceinline__ float bf2f(u16 h) {
    union { u32 u; float f; } v; v.u = ((u32)h) << 16;
    return v.f;
}

// ---------------------------------------------------------------------------
// Split+transpose weights: Wq[512,128] -> WqT hi/lo [128,512]; Wk[256,128] -> [128,256]
__global__ void prep_w(const float* __restrict__ Wq, const float* __restrict__ Wk,
                       u16* __restrict__ wqh, u16* __restrict__ wql,
                       u16* __restrict__ wkh, u16* __restrict__ wkl)
{
    const int t = blockIdx.x * 256 + threadIdx.x;
    if (t < 128 * 512) {
        const int n = t >> 9, k = t & 511;
        const float x = Wq[k * FG + n];
        const u16 h = f2bf(x);
        wqh[t] = h; wql[t] = f2bf(x - bf2f(h));
    } else {
        const int u = t - 128 * 512;
        const int n = u >> 8, k = u & 255;
        const float x = Wk[k * FG + n];
        const u16 h = f2bf(x);
        wkh[u] = h; wkl[u] = f2bf(x - bf2f(h));
    }
}

// ---------------------------------------------------------------------------
// v [32,1024,256] fp32 -> vT [32,256,1024] bf16
__global__ __launch_bounds__(256, 1)
void prep_v(const float* __restrict__ v, u16* __restrict__ vT)
{
    __shared__ u16 tile[64][72];
    const int tk0 = blockIdx.x * 64, d0 = blockIdx.y * 64, b = blockIdx.z;
    const int tid = threadIdx.x;
#pragma unroll
    for (int i = 0; i < 4; ++i) {
        const int f4 = i * 256 + tid;
        const int tkr = f4 >> 4, c4 = f4 & 15;
        f32x4 x = *reinterpret_cast<const f32x4*>(v + (u64)b * (TK * DV) + (u64)(tk0 + tkr) * DV + d0 + c4 * 4);
#pragma unroll
        for (int j = 0; j < 4; ++j) tile[tkr][c4 * 4 + j] = f2bf(x[j]);
    }
    __syncthreads();
#pragma unroll
    for (int i = 0; i < 2; ++i) {
        const int idx = i * 256 + tid;
        const int dr = idx >> 3, c8 = idx & 7;
        u16x8 o;
#pragma unroll
        for (int j = 0; j < 8; ++j) o[j] = tile[c8 * 8 + j][dr];
        *reinterpret_cast<u16x8*>(vT + (u64)b * (DV * TK) + (u64)(d0 + dr) * TK + tk0 + c8 * 8) = o;
    }
}

// ---------------------------------------------------------------------------
// Pack mask into per-lane bitmasks matching scores_kernel's layout.
// grid (32 qt, 32 b), 512 threads. Out: mb[((b*32+qt)*512+tid)*2 + {0,1}]
__global__ __launch_bounds__(512, 8)
void mask_pack(const int* __restrict__ mask, u32* __restrict__ mb)
{
    const int qt = blockIdx.x, b = blockIdx.y;
    const int row0 = qt * 32;
    const int tid = threadIdx.x;
    const int wid = tid >> 6, lane = tid & 63;
    const int l16 = lane & 15, l4 = lane >> 4;
    const int* mrow = mask + ((u64)b * TQ + row0) * TK;
    u32 mb0 = 0, mb1 = 0;
#pragma unroll
    for (int mf = 0; mf < 2; ++mf)
#pragma unroll
        for (int r = 0; r < 4; ++r) {
            const int row = mf * 16 + l4 * 4 + r;
#pragma unroll
            for (int nf = 0; nf < 8; ++nf) {
                const int col = wid * 128 + nf * 16 + l16;
                const int idx = mf * 32 + r * 8 + nf;
                const u32 bit = (mrow[(u64)row * TK + col] != 0) ? 1u : 0u;
                if (idx < 32) mb0 |= bit << idx; else mb1 |= bit << (idx - 32);
            }
        }
    const u64 o = ((u64)(b * 32 + qt) * 512 + tid) * 2;
    mb[o] = mb0; mb[o + 1] = mb1;
}

// ---------------------------------------------------------------------------
// Projection GEMM with split-bf16 (3-term) MFMA.
__global__ __launch_bounds__(256, 1)
void proj_kernel(const float* __restrict__ X, const u16* __restrict__ WTh,
                 const u16* __restrict__ WTl, u16* __restrict__ Oh,
                 u16* __restrict__ Ol, const int K, const float scale)
{
    __shared__ char qs[32768];
    char* qsh = qs;
    char* qsl = qs + 16384;
    const int tid = threadIdx.x;
    const int wid = tid >> 6, lane = tid & 63;
    const int l16 = lane & 15, l4 = lane >> 4;
    const int wm = wid >> 1, wn = wid & 1;
    const int rowbase = blockIdx.x * 64;

    f32x4 acc[2][4] = {};
    const int nchunks = K >> 7;
    for (int kc = 0; kc < nchunks; ++kc) {
        if (kc) __syncthreads();
#pragma unroll
        for (int i = 0; i < 8; ++i) {
            const int f4 = i * 256 + tid;
            const int r = f4 >> 5, c4 = f4 & 31;
            f32x4 x = *reinterpret_cast<const f32x4*>(X + (u64)(rowbase + r) * K + kc * 128 + c4 * 4);
            u16x4 hv, lv;
#pragma unroll
            for (int j = 0; j < 4; ++j) {
                const u16 h = f2bf(x[j]);
                hv[j] = h;
                lv[j] = f2bf(x[j] - bf2f(h));
            }
            const u32 a = r * 256 + ((u32)(c4 * 8) ^ ((r & 7) << 4));
            *reinterpret_cast<u16x4*>(qsh + a) = hv;
            *reinterpret_cast<u16x4*>(qsl + a) = lv;
        }
        __syncthreads();
#pragma unroll
        for (int kk = 0; kk < 4; ++kk) {
            bf16x8 ah[2], al[2];
#pragma unroll
            for (int mf = 0; mf < 2; ++mf) {
                const int r = wm * 32 + mf * 16 + l16;
                const u32 kb = kk * 64 + l4 * 16;
                const u32 a = r * 256 + (kb ^ ((u32)(r & 7) << 4));
                ah[mf] = *reinterpret_cast<const bf16x8*>(qsh + a);
                al[mf] = *reinterpret_cast<const bf16x8*>(qsl + a);
            }
#pragma unroll
            for (int nf = 0; nf < 4; ++nf) {
                const int col = wn * 64 + nf * 16 + l16;
                const u64 off = (u64)col * K + kc * 128 + kk * 32 + l4 * 8;
                bf16x8 bh = *reinterpret_cast<const bf16x8*>(WTh + off);
                bf16x8 bl = *reinterpret_cast<const bf16x8*>(WTl + off);
#pragma unroll
                for (int mf = 0; mf < 2; ++mf) {
                    acc[mf][nf] = __builtin_amdgcn_mfma_f32_16x16x32_bf16(ah[mf], bh, acc[mf][nf], 0, 0, 0);
                    acc[mf][nf] = __builtin_amdgcn_mfma_f32_16x16x32_bf16(ah[mf], bl, acc[mf][nf], 0, 0, 0);
                    acc[mf][nf] = __builtin_amdgcn_mfma_f32_16x16x32_bf16(al[mf], bh, acc[mf][nf], 0, 0, 0);
                }
            }
        }
    }
#pragma unroll
    for (int mf = 0; mf < 2; ++mf)
#pragma unroll
        for (int nf = 0; nf < 4; ++nf)
#pragma unroll
            for (int r = 0; r < 4; ++r) {
                const int row = rowbase + wm * 32 + mf * 16 + l4 * 4 + r;
                const int col = wn * 64 + nf * 16 + l16;
                const float xv = acc[mf][nf][r] * scale;
                const u16 h = f2bf(xv);
                Oh[(u64)row * FG + col] = h;
                Ol[(u64)row * FG + col] = f2bf(xv - bf2f(h));
            }
}

// ---------------------------------------------------------------------------
// Scores + mask + softmax + fp32 attn write.
// 1D grid 1024, XCD-swizzled: xcd=lin&7 owns batches [xcd*4, xcd*4+4).
// 512 threads (8 waves); wave w owns cols [w*128, w*128+128).
__global__ __launch_bounds__(512, 4)
void scores_kernel(const u16* __restrict__ qp_hi, const u16* __restrict__ qp_lo,
                   const u16* __restrict__ kp_hi, const u16* __restrict__ kp_lo,
                   const u32* __restrict__ mb, float* __restrict__ attn_out)
{
    __shared__ float red[256];
    __shared__ float rowstat[64];

    // XCD-aware swizzle: consecutive slots on an XCD share a batch -> kp stays L2-hot
    const int lin = blockIdx.x;
    const int xcd = lin & 7;
    const int slot = lin >> 3;              // 0..127
    const int b = xcd * 4 + (slot >> 5);    // 4 batches per XCD
    const int qt = slot & 31;

    const int row0 = qt * 32;
    const int tid = threadIdx.x;
    const int wid = tid >> 6;
    const int lane = tid & 63;
    const int l16 = lane & 15;
    const int l4  = lane >> 4;

    // packed mask: one 8B coalesced load per lane
    const u64 mo = ((u64)(b * 32 + qt) * 512 + tid) * 2;
    const u32 mb0 = mb[mo], mb1 = mb[mo + 1];

    // ---- scores (3-term split-bf16 MFMA); Q frags direct from global (L2-hot) ----
    f32x4 acc[2][8] = {};
    const u16* qph = qp_hi + (u64)(b * TQ + row0) * FG;
    const u16* qpl = qp_lo + (u64)(b * TQ + row0) * FG;
    const u16* kpbh = kp_hi + (u64)b * TK * FG;
    const u16* kpbl = kp_lo + (u64)b * TK * FG;

#pragma unroll
    for (int kk = 0; kk < 4; ++kk) {
        bf16x8 ah[2], al[2];
#pragma unroll
        for (int mf = 0; mf < 2; ++mf) {
            const u64 o = (u64)(mf * 16 + l16) * FG + kk * 32 + l4 * 8;
            ah[mf] = *reinterpret_cast<const bf16x8*>(qph + o);
            al[mf] = *reinterpret_cast<const bf16x8*>(qpl + o);
        }
#pragma unroll
        for (int nf = 0; nf < 8; ++nf) {
            const int col = wid * 128 + nf * 16 + l16;
            const u64 off = (u64)col * FG + kk * 32 + l4 * 8;
            bf16x8 bh = *reinterpret_cast<const bf16x8*>(kpbh + off);
            bf16x8 bl = *reinterpret_cast<const bf16x8*>(kpbl + off);
#pragma unroll
            for (int mf = 0; mf < 2; ++mf) {
                acc[mf][nf] = __builtin_amdgcn_mfma_f32_16x16x32_bf16(ah[mf], bh, acc[mf][nf], 0, 0, 0);
                acc[mf][nf] = __builtin_amdgcn_mfma_f32_16x16x32_bf16(ah[mf], bl, acc[mf][nf], 0, 0, 0);
                acc[mf][nf] = __builtin_amdgcn_mfma_f32_16x16x32_bf16(al[mf], bh, acc[mf][nf], 0, 0, 0);
            }
        }
    }

    // ---- mask apply (pure ALU) ----
#pragma unroll
    for (int mf = 0; mf < 2; ++mf)
#pragma unroll
        for (int r = 0; r < 4; ++r)
#pragma unroll
            for (int nf = 0; nf < 8; ++nf) {
                const int idx = mf * 32 + r * 8 + nf;
                const u32 bit = (idx < 32) ? (mb0 >> idx) : (mb1 >> (idx - 32));
                if (!(bit & 1)) acc[mf][nf][r] = -1e9f;
            }

    // ---- row max ----
#pragma unroll
    for (int mf = 0; mf < 2; ++mf)
#pragma unroll
        for (int r = 0; r < 4; ++r) {
            float m = acc[mf][0][r];
#pragma unroll
            for (int nf = 1; nf < 8; ++nf) m = fmaxf(m, acc[mf][nf][r]);
#pragma unroll
            for (int sh = 1; sh < 16; sh <<= 1) m = fmaxf(m, __shfl_xor(m, sh));
            if (l16 == 0) red[wid * 32 + mf * 16 + l4 * 4 + r] = m;
        }
    __syncthreads();
    if (tid < 32) {
        float m = red[tid];
#pragma unroll
        for (int w = 1; w < 8; ++w) m = fmaxf(m, red[w * 32 + tid]);
        rowstat[tid] = m;
    }
    __syncthreads();

    // ---- exp + row sum ----
#pragma unroll
    for (int mf = 0; mf < 2; ++mf)
#pragma unroll
        for (int r = 0; r < 4; ++r) {
            const int row = mf * 16 + l4 * 4 + r;
            const float m = rowstat[row];
            float s = 0.0f;
#pragma unroll
            for (int nf = 0; nf < 8; ++nf) {
                const float e = __expf(acc[mf][nf][r] - m);
                acc[mf][nf][r] = e;
                s += e;
            }
#pragma unroll
            for (int sh = 1; sh < 16; sh <<= 1) s += __shfl_xor(s, sh);
            if (l16 == 0) red[wid * 32 + row] = s;
        }
    __syncthreads();
    if (tid < 32) {
        float z = red[tid];
#pragma unroll
        for (int w = 1; w < 8; ++w) z += red[w * 32 + tid];
        rowstat[32 + tid] = 1.0f / z;
    }
    __syncthreads();

    // ---- normalize + fp32 attn write ----
    float* aout = attn_out + ((u64)b * TQ + row0) * TK;
#pragma unroll
    for (int mf = 0; mf < 2; ++mf)
#pragma unroll
        for (int r = 0; r < 4; ++r) {
            const int row = mf * 16 + l4 * 4 + r;
            const float rz = rowstat[32 + row];
#pragma unroll
            for (int nf = 0; nf < 8; ++nf) {
                const int col = wid * 128 + nf * 16 + l16;
                aout[(u64)row * TK + col] = acc[mf][nf][r] * rz;
            }
        }
}

// ---------------------------------------------------------------------------
// PV GEMM: ctx[b] = attn[b] (fp32->bf16) @ vT[b]^T.
// Block = 64 rows x ALL 256 d -> attn read exactly once. 512 threads, 2(m)x4(n) waves.
// 1D grid 512, XCD-swizzled (4 batches per XCD) so vT stays L2-hot.
__global__ __launch_bounds__(512, 4)
void pv_kernel(const float* __restrict__ attn, const u16* __restrict__ vT,
               float* __restrict__ ctx)
{
    __shared__ char as_[16384];   // [64][128] bf16 swizzled
    const int lin = blockIdx.x;
    const int xcd = lin & 7;
    const int slot = lin >> 3;              // 0..63
    const int b = xcd * 4 + (slot >> 4);
    const int mblk = slot & 15;

    const int row0 = mblk * 64;
    const int tid = threadIdx.x;
    const int wid = tid >> 6, lane = tid & 63;
    const int l16 = lane & 15, l4 = lane >> 4;
    const int wm = wid >> 2, wn = wid & 3;   // 2 x 4

    const float* Ab = attn + ((u64)b * TQ + row0) * TK;
    const u16*   Bb = vT + (u64)b * DV * TK;

    f32x4 acc[2][4] = {};
#pragma unroll 1
    for (int kc = 0; kc < 8; ++kc) {
        if (kc) __syncthreads();
        // stage attn [64 rows][128 k] fp32 -> bf16 swizzled LDS
#pragma unroll
        for (int i = 0; i < 4; ++i) {
            const int f4 = i * 512 + tid;
            const int r = f4 >> 5, c4 = f4 & 31;
            f32x4 x = *reinterpret_cast<const f32x4*>(Ab + (u64)r * TK + kc * 128 + c4 * 4);
            u16x4 hv;
#pragma unroll
            for (int j = 0; j < 4; ++j) hv[j] = f2bf(x[j]);
            const u32 a = r * 256 + ((u32)(c4 * 8) ^ ((r & 7) << 4));
            *reinterpret_cast<u16x4*>(as_ + a) = hv;
        }
        __syncthreads();
#pragma unroll
        for (int kk = 0; kk < 4; ++kk) {
            bf16x8 af[2];
#pragma unroll
            for (int mf = 0; mf < 2; ++mf) {
                const int r = wm * 32 + mf * 16 + l16;
                const u32 kb = kk * 64 + l4 * 16;
                af[mf] = *reinterpret_cast<const bf16x8*>(as_ + r * 256 + (kb ^ ((u32)(r & 7) << 4)));
            }
#pragma unroll
            for (int nf = 0; nf < 4; ++nf) {
                const int d = wn * 64 + nf * 16 + l16;
                bf16x8 bv = *reinterpret_cast<const bf16x8*>(Bb + (u64)d * TK + kc * 128 + kk * 32 + l4 * 8);
#pragma unroll
                for (int mf = 0; mf < 2; ++mf)
                    acc[mf][nf] = __builtin_amdgcn_mfma_f32_16x16x32_bf16(af[mf], bv, acc[mf][nf], 0, 0, 0);
            }
        }
    }
    float* cout = ctx + ((u64)b * TQ + row0) * DV;
#pragma unroll
    for (int mf = 0; mf < 2; ++mf)
#pragma unroll
        for (int nf = 0; nf < 4; ++nf)
#pragma unroll
            for (int r = 0; r < 4; ++r) {
                const int row = wm * 32 + mf * 16 + l4 * 4 + r;
                const int d = wn * 64 + nf * 16 + l16;
                cout[(u64)row * DV + d] = acc[mf][nf][r];
            }
}

// ---------------------------------------------------------------------------
extern "C" void kernel_launch(void* const* d_in, const int* in_sizes, int n_in,
                              void* d_out, int out_size, void* d_ws, size_t ws_size,
                              hipStream_t stream)
{
    const float* q    = (const float*)d_in[0];
    const float* k    = (const float*)d_in[1];
    const float* v    = (const float*)d_in[2];
    const int*   mask = (const int*)d_in[3];
    const float* Wq   = (const float*)d_in[4];
    const float* Wk   = (const float*)d_in[5];

    float* ctx  = (float*)d_out;
    float* attn = ctx + (u64)B_ * TQ * DV;

    u16* p = (u16*)d_ws;
    u16* qp_hi = p; p += (u64)B_ * TQ * FG;
    u16* qp_lo = p; p += (u64)B_ * TQ * FG;
    u16* kp_hi = p; p += (u64)B_ * TK * FG;
    u16* kp_lo = p; p += (u64)B_ * TK * FG;
    u16* vTb   = p; p += (u64)B_ * DV * TK;
    u16* wqh = p; p += 128 * 512;
    u16* wql = p; p += 128 * 512;
    u16* wkh = p; p += 128 * 256;
    u16* wkl = p; p += 128 * 256;
    u32* mb  = (u32*)p;   // 4 MB packed mask

    hipLaunchKernelGGL(mask_pack, dim3(32, 32), dim3(512), 0, stream, mask, mb);
    hipLaunchKernelGGL(prep_w, dim3(384), dim3(256), 0, stream, Wq, Wk, wqh, wql, wkh, wkl);
    hipLaunchKernelGGL(prep_v, dim3(16, 4, 32), dim3(256), 0, stream, v, vTb);
    hipLaunchKernelGGL(proj_kernel, dim3(512), dim3(256), 0, stream, q, wqh, wql, qp_hi, qp_lo, 512, 0.0625f);
    hipLaunchKernelGGL(proj_kernel, dim3(512), dim3(256), 0, stream, k, wkh, wkl, kp_hi, kp_lo, 256, 1.0f);
    hipLaunchKernelGGL(scores_kernel, dim3(1024), dim3(512), 0, stream,
                       qp_hi, qp_lo, kp_hi, kp_lo, mb, attn);
    hipLaunchKernelGGL(pv_kernel, dim3(512), dim3(512), 0, stream, attn, vTb, ctx);
}

// Round 5
// 223.464 us; speedup vs baseline: 1.4433x; 1.4090x over previous
//
#include <hip/hip_runtime.h>

typedef unsigned short u16;
typedef unsigned int   u32;
typedef unsigned long long u64;
typedef __attribute__((ext_vector_type(4))) float f32x4;
typedef __attribute__((ext_vector_type(8))) short bf16x8;
typedef __attribute__((ext_vector_type(4))) u16  u16x4;
typedef __attribute__((ext_vector_type(8))) u16  u16x8;
typedef __attribute__((ext_vector_type(4))) u32  u32x4;

#define B_  32
#define TQ  1024
#define TK  1024
#define FG  128
#define DV  256

__device__ __forceinline__ u16 f2bf(float x) {
    union { float f; u32 u; } v; v.f = x;
    u32 r = v.u + 0x7fffu + ((v.u >> 16) & 1u);   // RNE
    return (u16)(r >> 16);
}
__device__ __forceinline__ float bf2f(u16 h) {
    union { u32 u; float f; } v; v.u = ((u32)h) << 16;
    return v.f;
}

// ---------------------------------------------------------------------------
// prep_w: split Wq/Wk to bf16 hi/lo and store in MFMA FRAGMENT order:
// flat = ((colg*CK + ck)*64 + lane)*8 + e ; elem = (col=colg*16+l16, k=ck*32+l4*8+e)
__global__ void prep_w(const float* __restrict__ Wq, const float* __restrict__ Wk,
                       u16* __restrict__ wqh, u16* __restrict__ wql,
                       u16* __restrict__ wkh, u16* __restrict__ wkl)
{
    const int t = blockIdx.x * 256 + threadIdx.x;
    if (t < 65536) {
        const int k = t >> 7, n = t & 127;
        const float x = Wq[t];
        const u16 h = f2bf(x);
        const int colg = n >> 4, l16 = n & 15, ck = k >> 5, l4 = (k >> 3) & 3, e = k & 7;
        const int flat = (((colg * 16 + ck) * 4 + l4) * 16 + l16) * 8 + e;  // CK=16
        wqh[flat] = h; wql[flat] = f2bf(x - bf2f(h));
    } else {
        const int u = t - 65536;
        const int k = u >> 7, n = u & 127;
        const float x = Wk[u];
        const u16 h = f2bf(x);
        const int colg = n >> 4, l16 = n & 15, ck = k >> 5, l4 = (k >> 3) & 3, e = k & 7;
        const int flat = (((colg * 8 + ck) * 4 + l4) * 16 + l16) * 8 + e;   // CK=8
        wkh[flat] = h; wkl[flat] = f2bf(x - bf2f(h));
    }
}

// ---------------------------------------------------------------------------
// v [32,1024,256] fp32 -> vT fragments: [b][g=d/16][ks=kv/32][lane][8]
// elem = (d = g*16+l16, kv = ks*32 + l4*8 + e)
__global__ __launch_bounds__(256, 1)
void prep_v(const float* __restrict__ v, u16* __restrict__ vtf)
{
    __shared__ u16 tile[64][72];
    const int tk0 = blockIdx.x * 64, d0 = blockIdx.y * 64, b = blockIdx.z;
    const int tid = threadIdx.x;
#pragma unroll
    for (int i = 0; i < 4; ++i) {
        const int f4 = i * 256 + tid;
        const int tkr = f4 >> 4, c4 = f4 & 15;
        f32x4 x = *reinterpret_cast<const f32x4*>(v + (u64)b * (TK * DV) + (u64)(tk0 + tkr) * DV + d0 + c4 * 4);
#pragma unroll
        for (int j = 0; j < 4; ++j) tile[tkr][c4 * 4 + j] = f2bf(x[j]);
    }
    __syncthreads();
#pragma unroll
    for (int pass = 0; pass < 2; ++pass) {
        const int idx = pass * 256 + tid;           // 512 units: [g_l(4)][ks_l(2)][lane(64)]
        const int g_l = idx >> 7, ks_l = (idx >> 6) & 1, lane2 = idx & 63;
        const int l4b = lane2 >> 4, l16b = lane2 & 15;
        const int d_l = g_l * 16 + l16b, kv_l = ks_l * 32 + l4b * 8;
        u16x8 o;
#pragma unroll
        for (int e = 0; e < 8; ++e) o[e] = tile[kv_l + e][d_l];
        const u64 flat = (((u64)(b * 16 + (d0 >> 4) + g_l) * 32 + (tk0 >> 5) + ks_l) * 64 + lane2) * 8;
        *reinterpret_cast<u16x8*>(vtf + flat) = o;
    }
}

// ---------------------------------------------------------------------------
// Pack mask into per-lane bitmasks matching the fused kernel's layout.
__global__ __launch_bounds__(512, 8)
void mask_pack(const int* __restrict__ mask, u32* __restrict__ mb)
{
    const int qt = blockIdx.x, b = blockIdx.y;
    const int row0 = qt * 32;
    const int tid = threadIdx.x;
    const int wid = tid >> 6, lane = tid & 63;
    const int l16 = lane & 15, l4 = lane >> 4;
    const int* mrow = mask + ((u64)b * TQ + row0) * TK;
    u32 mb0 = 0, mb1 = 0;
#pragma unroll
    for (int mf = 0; mf < 2; ++mf)
#pragma unroll
        for (int r = 0; r < 4; ++r) {
            const int row = mf * 16 + l4 * 4 + r;
#pragma unroll
            for (int nf = 0; nf < 8; ++nf) {
                const int col = wid * 128 + nf * 16 + l16;
                const int idx = mf * 32 + r * 8 + nf;
                const u32 bit = (mrow[(u64)row * TK + col] != 0) ? 1u : 0u;
                if (idx < 32) mb0 |= bit << idx; else mb1 |= bit << (idx - 32);
            }
        }
    const u64 o = ((u64)(b * 32 + qt) * 512 + tid) * 2;
    mb[o] = mb0; mb[o + 1] = mb1;
}

// ---------------------------------------------------------------------------
// Projection GEMM, split-bf16 3-term. W read in fragment order (coalesced).
// Output written in fragment order: [tokg][kk][lane][8] via LDS transpose.
__global__ __launch_bounds__(256, 1)
void proj_kernel(const float* __restrict__ X, const u16* __restrict__ WfH,
                 const u16* __restrict__ WfL, u16* __restrict__ Ofh,
                 u16* __restrict__ Ofl, const int K, const int CK, const float scale)
{
    __shared__ char qs[32768];
    char* qsh = qs;
    char* qsl = qs + 16384;
    const int tid = threadIdx.x;
    const int wid = tid >> 6, lane = tid & 63;
    const int l16 = lane & 15, l4 = lane >> 4;
    const int wm = wid >> 1, wn = wid & 1;
    const int rowbase = blockIdx.x * 64;

    f32x4 acc[2][4] = {};
    const int nchunks = K >> 7;
    for (int kc = 0; kc < nchunks; ++kc) {
        if (kc) __syncthreads();
#pragma unroll
        for (int i = 0; i < 8; ++i) {
            const int f4 = i * 256 + tid;
            const int r = f4 >> 5, c4 = f4 & 31;
            f32x4 x = *reinterpret_cast<const f32x4*>(X + (u64)(rowbase + r) * K + kc * 128 + c4 * 4);
            u16x4 hv, lv;
#pragma unroll
            for (int j = 0; j < 4; ++j) {
                const u16 h = f2bf(x[j]);
                hv[j] = h;
                lv[j] = f2bf(x[j] - bf2f(h));
            }
            const u32 a = r * 256 + ((u32)(c4 * 8) ^ ((r & 7) << 4));
            *reinterpret_cast<u16x4*>(qsh + a) = hv;
            *reinterpret_cast<u16x4*>(qsl + a) = lv;
        }
        __syncthreads();
#pragma unroll
        for (int kk = 0; kk < 4; ++kk) {
            bf16x8 ah[2], al[2];
#pragma unroll
            for (int mf = 0; mf < 2; ++mf) {
                const int r = wm * 32 + mf * 16 + l16;
                const u32 kb = kk * 64 + l4 * 16;
                const u32 a = r * 256 + (kb ^ ((u32)(r & 7) << 4));
                ah[mf] = *reinterpret_cast<const bf16x8*>(qsh + a);
                al[mf] = *reinterpret_cast<const bf16x8*>(qsl + a);
            }
#pragma unroll
            for (int nf = 0; nf < 4; ++nf) {
                const u64 off = ((u64)((wn * 4 + nf) * CK + kc * 4 + kk)) * 512 + lane * 8;
                bf16x8 bh = *reinterpret_cast<const bf16x8*>(WfH + off);
                bf16x8 bl = *reinterpret_cast<const bf16x8*>(WfL + off);
#pragma unroll
                for (int mf = 0; mf < 2; ++mf) {
                    acc[mf][nf] = __builtin_amdgcn_mfma_f32_16x16x32_bf16(ah[mf], bh, acc[mf][nf], 0, 0, 0);
                    acc[mf][nf] = __builtin_amdgcn_mfma_f32_16x16x32_bf16(ah[mf], bl, acc[mf][nf], 0, 0, 0);
                    acc[mf][nf] = __builtin_amdgcn_mfma_f32_16x16x32_bf16(al[mf], bh, acc[mf][nf], 0, 0, 0);
                }
            }
        }
    }
    // ---- epilogue: scale+split -> LDS bf16 planes -> fragment-order stores ----
    __syncthreads();
#pragma unroll
    for (int mf = 0; mf < 2; ++mf)
#pragma unroll
        for (int nf = 0; nf < 4; ++nf)
#pragma unroll
            for (int r = 0; r < 4; ++r) {
                const int tok = wm * 32 + mf * 16 + l4 * 4 + r;
                const int fg  = wn * 64 + nf * 16 + l16;
                const float xv = acc[mf][nf][r] * scale;
                const u16 h = f2bf(xv);
                const u32 a = tok * 256 + ((u32)(fg * 2) ^ ((tok & 7) << 4));
                *reinterpret_cast<u16*>(qsh + a) = h;
                *reinterpret_cast<u16*>(qsl + a) = f2bf(xv - bf2f(h));
            }
    __syncthreads();
#pragma unroll
    for (int pass = 0; pass < 4; ++pass) {
        const int idx = pass * 256 + tid;        // [tokg_l(4)][kk(4)][lane(64)]
        const int tokg_l = idx >> 8, kk2 = (idx >> 6) & 3, lane2 = idx & 63;
        const int l4b = lane2 >> 4, l16b = lane2 & 15;
        const int tok = tokg_l * 16 + l16b;
        const u32 fgb = (u32)(kk2 * 64 + l4b * 16);
        const u32 a = tok * 256 + (fgb ^ ((u32)(tok & 7) << 4));
        u16x8 vh = *reinterpret_cast<const u16x8*>(qsh + a);
        u16x8 vl = *reinterpret_cast<const u16x8*>(qsl + a);
        const u64 flat = ((u64)(((rowbase >> 4) + tokg_l) * 4 + kk2) * 64 + lane2) * 8;
        *reinterpret_cast<u16x8*>(Ofh + flat) = vh;
        *reinterpret_cast<u16x8*>(Ofl + flat) = vl;
    }
}

// ---------------------------------------------------------------------------
// Fused scores + mask + softmax + attn-write + PV. All operands fragment-packed.
// 1D grid 1024 XCD-swizzled; 512 threads (8 waves); wave w owns score cols [w*128,+128)
// and ctx d-cols [w*32,+32).
__global__ __launch_bounds__(512, 4)
void attn_fused(const u16* __restrict__ qpf_h, const u16* __restrict__ qpf_l,
                const u16* __restrict__ kpf_h, const u16* __restrict__ kpf_l,
                const u16* __restrict__ vtf, const u32* __restrict__ mb,
                float* __restrict__ attn_out, float* __restrict__ ctx_out)
{
    extern __shared__ char smem[];
    char* as_ = smem;                                 // P bf16 [32][1024] swizzled, 64KB
    float* red     = (float*)(smem + 65536);          // [8][32]
    float* rowstat = red + 256;                       // [0..31]=rowmax, [32..63]=1/Z

    const int lin = blockIdx.x;
    const int xcd = lin & 7;
    const int slot = lin >> 3;
    const int b = xcd * 4 + (slot >> 5);
    const int qt = slot & 31;

    const int row0 = qt * 32;
    const int tid = threadIdx.x;
    const int wid = tid >> 6;
    const int lane = tid & 63;
    const int l16 = lane & 15;
    const int l4  = lane >> 4;

    // packed mask: one 8B coalesced load per lane
    const u64 mo = ((u64)(b * 32 + qt) * 512 + tid) * 2;
    const u32 mb0 = mb[mo], mb1 = mb[mo + 1];

    // ---- QK^T (3-term split-bf16), fragment loads: 16B/lane fully coalesced ----
    f32x4 acc[2][8] = {};
    const int qtg = b * 64 + qt * 2;
#pragma unroll
    for (int kk = 0; kk < 4; ++kk) {
        bf16x8 ah[2], al[2];
#pragma unroll
        for (int mf = 0; mf < 2; ++mf) {
            const u64 o = ((u64)((qtg + mf) * 4 + kk) * 64 + lane) * 8;
            ah[mf] = *reinterpret_cast<const bf16x8*>(qpf_h + o);
            al[mf] = *reinterpret_cast<const bf16x8*>(qpf_l + o);
        }
#pragma unroll
        for (int nf = 0; nf < 8; ++nf) {
            const int colg = b * 64 + wid * 8 + nf;
            const u64 off = ((u64)(colg * 4 + kk) * 64 + lane) * 8;
            bf16x8 bh = *reinterpret_cast<const bf16x8*>(kpf_h + off);
            bf16x8 bl = *reinterpret_cast<const bf16x8*>(kpf_l + off);
#pragma unroll
            for (int mf = 0; mf < 2; ++mf) {
                acc[mf][nf] = __builtin_amdgcn_mfma_f32_16x16x32_bf16(ah[mf], bh, acc[mf][nf], 0, 0, 0);
                acc[mf][nf] = __builtin_amdgcn_mfma_f32_16x16x32_bf16(ah[mf], bl, acc[mf][nf], 0, 0, 0);
                acc[mf][nf] = __builtin_amdgcn_mfma_f32_16x16x32_bf16(al[mf], bh, acc[mf][nf], 0, 0, 0);
            }
        }
    }

    // ---- mask apply (pure ALU) ----
#pragma unroll
    for (int mf = 0; mf < 2; ++mf)
#pragma unroll
        for (int r = 0; r < 4; ++r)
#pragma unroll
            for (int nf = 0; nf < 8; ++nf) {
                const int idx = mf * 32 + r * 8 + nf;
                const u32 bit = (idx < 32) ? (mb0 >> idx) : (mb1 >> (idx - 32));
                if (!(bit & 1)) acc[mf][nf][r] = -1e9f;
            }

    // ---- row max ----
#pragma unroll
    for (int mf = 0; mf < 2; ++mf)
#pragma unroll
        for (int r = 0; r < 4; ++r) {
            float m = acc[mf][0][r];
#pragma unroll
            for (int nf = 1; nf < 8; ++nf) m = fmaxf(m, acc[mf][nf][r]);
#pragma unroll
            for (int sh = 1; sh < 16; sh <<= 1) m = fmaxf(m, __shfl_xor(m, sh));
            if (l16 == 0) red[wid * 32 + mf * 16 + l4 * 4 + r] = m;
        }
    __syncthreads();
    if (tid < 32) {
        float m = red[tid];
#pragma unroll
        for (int w = 1; w < 8; ++w) m = fmaxf(m, red[w * 32 + tid]);
        rowstat[tid] = m;
    }
    __syncthreads();

    // ---- exp + row sum ----
#pragma unroll
    for (int mf = 0; mf < 2; ++mf)
#pragma unroll
        for (int r = 0; r < 4; ++r) {
            const int row = mf * 16 + l4 * 4 + r;
            const float m = rowstat[row];
            float s = 0.0f;
#pragma unroll
            for (int nf = 0; nf < 8; ++nf) {
                const float e = __expf(acc[mf][nf][r] - m);
                acc[mf][nf][r] = e;
                s += e;
            }
#pragma unroll
            for (int sh = 1; sh < 16; sh <<= 1) s += __shfl_xor(s, sh);
            if (l16 == 0) red[wid * 32 + row] = s;
        }
    __syncthreads();
    if (tid < 32) {
        float z = red[tid];
#pragma unroll
        for (int w = 1; w < 8; ++w) z += red[w * 32 + tid];
        rowstat[32 + tid] = 1.0f / z;
    }
    __syncthreads();

    // ---- normalize -> bf16 into swizzled LDS P-tile ----
#pragma unroll
    for (int mf = 0; mf < 2; ++mf)
#pragma unroll
        for (int r = 0; r < 4; ++r) {
            const int row = mf * 16 + l4 * 4 + r;
            const float rz = rowstat[32 + row];
#pragma unroll
            for (int nf = 0; nf < 8; ++nf) {
                const int col = wid * 128 + nf * 16 + l16;
                const u32 cb = (u32)(col * 2);
                *reinterpret_cast<u16*>(as_ + row * 2048 + (cb ^ ((u32)(row & 7) << 4))) =
                    f2bf(acc[mf][nf][r] * rz);
            }
        }
    __syncthreads();

    // ---- attn write: coalesced readback of the LDS P-tile (32B/lane contiguous) ----
    float* aout = attn_out + ((u64)b * TQ + row0) * TK;
#pragma unroll
    for (int i = 0; i < 8; ++i) {
        const int flat = i * 4096 + tid * 8;
        const int row = flat >> 10, col = flat & 1023;
        u16x8 p8 = *reinterpret_cast<const u16x8*>(as_ + row * 2048 + (((u32)(col * 2)) ^ ((u32)(row & 7) << 4)));
        f32x4 o0, o1;
#pragma unroll
        for (int j = 0; j < 4; ++j) { o0[j] = bf2f(p8[j]); o1[j] = bf2f(p8[4 + j]); }
        *reinterpret_cast<f32x4*>(aout + (u64)row * TK + col) = o0;
        *reinterpret_cast<f32x4*>(aout + (u64)row * TK + col + 4) = o1;
    }

    // ---- PV: ctx[32,256] = P @ V; vT fragment loads coalesced ----
    f32x4 acc2[2][2] = {};
#pragma unroll 4
    for (int ks = 0; ks < 32; ++ks) {
        bf16x8 pa[2];
#pragma unroll
        for (int mf = 0; mf < 2; ++mf) {
            const int r = mf * 16 + l16;
            const u32 kb = ks * 64 + l4 * 16;
            pa[mf] = *reinterpret_cast<const bf16x8*>(as_ + r * 2048 + (kb ^ ((u32)(r & 7) << 4)));
        }
#pragma unroll
        for (int nf2 = 0; nf2 < 2; ++nf2) {
            const int g = b * 16 + wid * 2 + nf2;
            bf16x8 bv = *reinterpret_cast<const bf16x8*>(vtf + ((u64)(g * 32 + ks) * 64 + lane) * 8);
#pragma unroll
            for (int mf = 0; mf < 2; ++mf)
                acc2[mf][nf2] = __builtin_amdgcn_mfma_f32_16x16x32_bf16(pa[mf], bv, acc2[mf][nf2], 0, 0, 0);
        }
    }
    float* cout = ctx_out + ((u64)b * TQ + row0) * DV;
#pragma unroll
    for (int mf = 0; mf < 2; ++mf)
#pragma unroll
        for (int nf2 = 0; nf2 < 2; ++nf2)
#pragma unroll
            for (int r = 0; r < 4; ++r) {
                const int row = mf * 16 + l4 * 4 + r;
                const int d = wid * 32 + nf2 * 16 + l16;
                cout[(u64)row * DV + d] = acc2[mf][nf2][r];
            }
}

// ---------------------------------------------------------------------------
extern "C" void kernel_launch(void* const* d_in, const int* in_sizes, int n_in,
                              void* d_out, int out_size, void* d_ws, size_t ws_size,
                              hipStream_t stream)
{
    const float* q    = (const float*)d_in[0];
    const float* k    = (const float*)d_in[1];
    const float* v    = (const float*)d_in[2];
    const int*   mask = (const int*)d_in[3];
    const float* Wq   = (const float*)d_in[4];
    const float* Wk   = (const float*)d_in[5];

    float* ctx  = (float*)d_out;
    float* attn = ctx + (u64)B_ * TQ * DV;

    u16* p = (u16*)d_ws;
    u16* qpf_h = p; p += (u64)B_ * TQ * FG;
    u16* qpf_l = p; p += (u64)B_ * TQ * FG;
    u16* kpf_h = p; p += (u64)B_ * TK * FG;
    u16* kpf_l = p; p += (u64)B_ * TK * FG;
    u16* vtf   = p; p += (u64)B_ * DV * TK;
    u16* wqf_h = p; p += 128 * 512;
    u16* wqf_l = p; p += 128 * 512;
    u16* wkf_h = p; p += 128 * 256;
    u16* wkf_l = p; p += 128 * 256;
    u32* mb  = (u32*)p;   // 4 MB packed mask

    hipLaunchKernelGGL(mask_pack, dim3(32, 32), dim3(512), 0, stream, mask, mb);
    hipLaunchKernelGGL(prep_w, dim3(384), dim3(256), 0, stream, Wq, Wk, wqf_h, wqf_l, wkf_h, wkf_l);
    hipLaunchKernelGGL(prep_v, dim3(16, 4, 32), dim3(256), 0, stream, v, vtf);
    hipLaunchKernelGGL(proj_kernel, dim3(512), dim3(256), 0, stream, q, wqf_h, wqf_l, qpf_h, qpf_l, 512, 16, 0.0625f);
    hipLaunchKernelGGL(proj_kernel, dim3(512), dim3(256), 0, stream, k, wkf_h, wkf_l, kpf_h, kpf_l, 256, 8, 1.0f);

    const int lds = 65536 + 256 * 4 + 64 * 4;
    (void)hipFuncSetAttribute(reinterpret_cast<const void*>(attn_fused),
                              hipFuncAttributeMaxDynamicSharedMemorySize, lds);
    hipLaunchKernelGGL(attn_fused, dim3(1024), dim3(512), lds, stream,
                       qpf_h, qpf_l, kpf_h, kpf_l, vtf, mb, attn, ctx);
}